// Round 15
// baseline (726.028 us; speedup 1.0000x reference)
//
#include <hip/hip_runtime.h>
#include <cstddef>

typedef __attribute__((ext_vector_type(8))) short bf16x8;
typedef __attribute__((ext_vector_type(8), aligned(8))) short bf16x8a;
typedef __attribute__((ext_vector_type(4))) float f32x4;
typedef __attribute__((ext_vector_type(4))) unsigned short u16x4;

__device__ inline unsigned short f2bf(float f) {
  unsigned int u = __float_as_uint(f);
  unsigned int r = (u + 0x7FFFu + ((u >> 16) & 1u)) >> 16;
  return (unsigned short)r;
}
__device__ inline float bf2f(unsigned short u) {
  return __uint_as_float((unsigned int)u << 16);
}

// ---------------- prep: x (32,3,152,152) f32 -> xb1 bf16 [b][ih152][iw160][ic4]
__global__ __launch_bounds__(256) void prep_xb1(const float* __restrict__ x,
                                                unsigned short* __restrict__ xb) {
  const int j = blockIdx.x * 256 + threadIdx.x;   // 32*152*160 = 778240 exact
  const int iw = j % 160;
  const int ih = (j / 160) % 152;
  const int b = j / (160 * 152);
  unsigned short v[4] = {0, 0, 0, 0};
  if (iw < 152) {
    #pragma unroll
    for (int ic = 0; ic < 3; ++ic)
      v[ic] = f2bf(x[((size_t)(b * 3 + ic) * 152 + ih) * 152 + iw]);
  }
  *(unsigned long long*)(xb + (size_t)j * 4) = *(unsigned long long*)v;
}

// ---------------- prep: conv1 w (32,3,11,11) -> A-table wb1 [step17][kc4][s32][8]
__global__ __launch_bounds__(256) void prep_wb1(const float* __restrict__ w,
                                                unsigned short* __restrict__ wb) {
  const int j = blockIdx.x * 256 + threadIdx.x;   // 17408 exact
  const int e = j & 7;
  const int s = (j >> 3) & 31;
  const int kcj = j >> 8;
  const int kc = kcj & 3, step = kcj >> 2;
  const int t = step * 8 + kc * 2 + (e >> 2);
  const int ics = e & 3;
  const int kh = t / 12, kwp = t - kh * 12;
  float val = 0.f;
  if (t < 132 && kwp < 11 && ics < 3)
    val = w[((s * 3 + ics) * 11 + kh) * 11 + kwp];
  wb[j] = f2bf(val);
}

// ---------------- conv1 via MFMA (proven): writes c1T bf16 [oc32][pos20164][b32]
__global__ __launch_bounds__(256, 4) void conv1_mfma(const unsigned short* __restrict__ xb,
                                                     const unsigned short* __restrict__ wb,
                                                     const float* __restrict__ bias,
                                                     unsigned short* __restrict__ outT) {
  const int lane = threadIdx.x & 63;
  const int wvi = threadIdx.x >> 6;
  const int pos = blockIdx.x * 4 + wvi;
  const int oh = pos / 142, ow = pos % 142;
  const int row = lane & 15;
  const int kc = lane >> 4;
  f32x4 a00 = {0.f, 0.f, 0.f, 0.f}, a01 = a00, a10 = a00, a11 = a00;
  const size_t xbase = ((size_t)row * 152 + oh) * 160 + ow;

  #pragma unroll 2
  for (int j = 0; j < 17; ++j) {
    const int t0 = j * 8 + 2 * kc;
    int kh = t0 / 12;
    int kwp = t0 - kh * 12;
    if (t0 >= 132) { kh = 0; kwp = 0; }
    const bf16x8 wa0 = *(const bf16x8*)(wb + (((j * 4 + kc) * 32) + row) * 8);
    const bf16x8 wa1 = *(const bf16x8*)(wb + (((j * 4 + kc) * 32) + 16 + row) * 8);
    const unsigned short* xp = xb + (xbase + kh * 160 + kwp) * 4;
    const bf16x8 xv0 = *(const bf16x8a*)(xp);
    const bf16x8 xv1 = *(const bf16x8a*)(xp + 16 * 152 * 160 * 4);
    a00 = __builtin_amdgcn_mfma_f32_16x16x32_bf16(wa0, xv0, a00, 0, 0, 0);
    a01 = __builtin_amdgcn_mfma_f32_16x16x32_bf16(wa0, xv1, a01, 0, 0, 0);
    a10 = __builtin_amdgcn_mfma_f32_16x16x32_bf16(wa1, xv0, a10, 0, 0, 0);
    a11 = __builtin_amdgcn_mfma_f32_16x16x32_bf16(wa1, xv1, a11, 0, 0, 0);
  }

  #pragma unroll
  for (int r = 0; r < 4; ++r) {
    const int ocl = kc * 4 + r;
    const float bv0 = bias[ocl];
    const float bv1 = bias[16 + ocl];
    outT[((size_t)ocl * 20164 + pos) * 32 + row] = f2bf(fmaxf(a00[r] + bv0, 0.f));
    outT[((size_t)ocl * 20164 + pos) * 32 + 16 + row] = f2bf(fmaxf(a01[r] + bv0, 0.f));
    outT[((size_t)(16 + ocl) * 20164 + pos) * 32 + row] = f2bf(fmaxf(a10[r] + bv1, 0.f));
    outT[((size_t)(16 + ocl) * 20164 + pos) * 32 + 16 + row] = f2bf(fmaxf(a11[r] + bv1, 0.f));
  }
}

// ---------------- fused maxpool(3,2,1) + transpose -> xb2 [pos'5041][b32][c32] bf16
__global__ __launch_bounds__(256) void pool_t(const unsigned short* __restrict__ in,
                                              unsigned short* __restrict__ xb) {
  __shared__ float tile[8][32][33];
  const int ohp = blockIdx.x;
  const int t8 = blockIdx.y;
  const int tid = threadIdx.x;
  const int b = tid & 31, pg = tid >> 5;
  const int owp = min(t8 * 8 + pg, 70);

  for (int c = 0; c < 32; ++c) {
    float m = 0.f;
    #pragma unroll
    for (int kh = 0; kh < 3; ++kh) {
      const int ih = ohp * 2 - 1 + kh;
      if (ih < 0 || ih >= 142) continue;
      #pragma unroll
      for (int kw = 0; kw < 3; ++kw) {
        const int iw = owp * 2 - 1 + kw;
        if (iw < 0 || iw >= 142) continue;
        m = fmaxf(m, bf2f(in[((size_t)c * 20164 + ih * 142 + iw) * 32 + b]));
      }
    }
    tile[pg][b][c] = m;
  }
  __syncthreads();

  if (t8 * 8 + pg < 71) {
    const int posp = ohp * 71 + t8 * 8 + pg;
    #pragma unroll
    for (int cc = 0; cc < 32; cc += 8) {
      bf16x8 pack;
      #pragma unroll
      for (int e = 0; e < 8; ++e) pack[e] = (short)f2bf(tile[pg][b][cc + e]);
      *(bf16x8*)(xb + ((size_t)posp * 32 + b) * 32 + cc) = pack;
    }
  }
}

// ---------------- wb2: conv2 w (16,32,9,9) -> [sp81][oc16][ic32] bf16
__global__ __launch_bounds__(256) void prep_wb2(const float* __restrict__ w,
                                                unsigned short* __restrict__ wb) {
  const int j = blockIdx.x * 256 + threadIdx.x;
  if (j >= 81 * 16 * 32) return;
  const int ic = j & 31, oc = (j >> 5) & 15, sp = j >> 9;
  wb[j] = f2bf(w[(size_t)oc * 2592 + ic * 81 + sp]);
}

// ---------------- conv2 via MFMA; writes h2b bf16 [pos][b32][oc16]
__global__ __launch_bounds__(256) void conv2_mfma(const unsigned short* __restrict__ xb,
                                                  const unsigned short* __restrict__ wb,
                                                  const float* __restrict__ bias,
                                                  unsigned short* __restrict__ outB) {
  const int lane = threadIdx.x & 63;
  const int wvi = threadIdx.x >> 6;
  int pos = blockIdx.x * 4 + wvi;
  if (pos > 3968) pos = 3968;
  const int oh = pos / 63, ow = pos % 63;
  const int row = lane & 15;                      // b column
  const int kc = lane >> 4;
  f32x4 acc0 = {0.f, 0.f, 0.f, 0.f}, acc1 = {0.f, 0.f, 0.f, 0.f};
  const unsigned short* xbase = xb + (size_t)(oh * 71 + ow) * 1024;
  const int aoff = row * 32 + kc * 8;
  const int boff0 = aoff;
  const int boff1 = (row + 16) * 32 + kc * 8;

  #pragma unroll
  for (int kh = 0; kh < 9; ++kh) {
    #pragma unroll
    for (int kw = 0; kw < 9; ++kw) {
      const int sp = kh * 9 + kw;
      const bf16x8 a = *(const bf16x8*)(wb + sp * 512 + aoff);
      const unsigned short* xp = xbase + (kh * 71 + kw) * 1024;
      const bf16x8 b0 = *(const bf16x8*)(xp + boff0);
      const bf16x8 b1 = *(const bf16x8*)(xp + boff1);
      acc0 = __builtin_amdgcn_mfma_f32_16x16x32_bf16(a, b0, acc0, 0, 0, 0);
      acc1 = __builtin_amdgcn_mfma_f32_16x16x32_bf16(a, b1, acc1, 0, 0, 0);
    }
  }

  u16x4 pk0, pk1;
  #pragma unroll
  for (int r = 0; r < 4; ++r) {
    const float bv = bias[kc * 4 + r];
    pk0[r] = f2bf(fmaxf(acc0[r] + bv, 0.f));
    pk1[r] = f2bf(fmaxf(acc1[r] + bv, 0.f));
  }
  *(u16x4*)(outB + (size_t)pos * 512 + row * 16 + kc * 4) = pk0;
  *(u16x4*)(outB + (size_t)pos * 512 + (row + 16) * 16 + kc * 4) = pk1;
}

// ---------------- lc via MFMA v2: weights streamed f32->bf16 through LDS in-kernel.
// Block = 4 waves = 4 positions; per group of G=7 pairs all 256 threads stage
// the f32 weights (coalesced), convert, store A-fragments in LDS (padded rows).
// in xb [IH*IH][b32][ic16] bf16; out [NPOS][b32][oc16] bf16; bias[oc][NPOS].
template <int KH, int S, int IH, int OH>
__global__ __launch_bounds__(256) void lc_mfma2(const unsigned short* __restrict__ xb,
                                                const float* __restrict__ w,
                                                const float* __restrict__ bias,
                                                unsigned short* __restrict__ out) {
  constexpr int KHW = KH * KH;
  constexpr int P = (KHW + 1) / 2;            // 41 / 25 / 13 pairs
  constexpr int G = 7;                        // pairs per group
  constexpr int NG = (P + G - 1) / G;         // 6 / 4 / 2 groups
  constexpr int T = 2 * G;                    // taps staged per group
  constexpr int NPOS = OH * OH;
  __shared__ unsigned short wsh[4][G][16][40];  // padded row: 32->40 bf16

  const int tid = threadIdx.x;
  const int lane = tid & 63;
  const int wvi = tid >> 6;
  int pos = blockIdx.x * 4 + wvi;
  if (pos >= NPOS) pos = NPOS - 1;
  const int oh = pos / OH, ow = pos % OH;
  const int bcol = lane & 15;
  const int kc = lane >> 4;
  const int tsel = kc >> 1;
  const int icoff = (kc & 1) * 8;
  f32x4 acc0 = {0.f, 0.f, 0.f, 0.f}, acc1 = {0.f, 0.f, 0.f, 0.f};
  const int xorg = (oh * S) * IH + ow * S;

  for (int g = 0; g < NG; ++g) {
    __syncthreads();
    for (int idx = tid; idx < 4 * 256 * T; idx += 256) {
      const int tl = idx % T;
      const int ocic = (idx / T) & 255;
      const int posl = idx / (T * 256);
      const int tap = g * T + tl;
      int pp = blockIdx.x * 4 + posl;
      if (pp >= NPOS) pp = NPOS - 1;
      float v = 0.f;
      if (tap < KHW) v = w[((size_t)pp * 256 + ocic) * KHW + tap];
      wsh[posl][tl >> 1][ocic >> 4][(tl & 1) * 16 + (ocic & 15)] = f2bf(v);
    }
    __syncthreads();
    #pragma unroll
    for (int pg = 0; pg < G; ++pg) {
      const int p = g * G + pg;
      const int t0 = (2 * p < KHW) ? 2 * p : 0;
      const int t1 = (2 * p + 1 < KHW) ? 2 * p + 1 : 0;
      const int o0 = (t0 / KH) * IH + (t0 % KH);
      const int o1 = (t1 / KH) * IH + (t1 % KH);
      const int osel = tsel ? o1 : o0;
      const bf16x8 a = *(const bf16x8*)&wsh[wvi][pg][bcol][kc * 8];
      const unsigned short* xp = xb + (size_t)(xorg + osel) * 512 + icoff;
      const bf16x8 b0 = *(const bf16x8*)(xp + bcol * 16);
      const bf16x8 b1 = *(const bf16x8*)(xp + (bcol + 16) * 16);
      acc0 = __builtin_amdgcn_mfma_f32_16x16x32_bf16(a, b0, acc0, 0, 0, 0);
      acc1 = __builtin_amdgcn_mfma_f32_16x16x32_bf16(a, b1, acc1, 0, 0, 0);
    }
  }

  u16x4 pk0, pk1;
  #pragma unroll
  for (int r = 0; r < 4; ++r) {
    const float bv = bias[(kc * 4 + r) * NPOS + pos];
    pk0[r] = f2bf(fmaxf(acc0[r] + bv, 0.f));
    pk1[r] = f2bf(fmaxf(acc1[r] + bv, 0.f));
  }
  *(u16x4*)(out + (size_t)pos * 512 + bcol * 16 + kc * 4) = pk0;
  *(u16x4*)(out + (size_t)pos * 512 + (bcol + 16) * 16 + kc * 4) = pk1;
}

// ---------------- reformat lc3 out [pos441][b32][oc16] bf16 -> h5T f32 [oc*441+pos][b32]
__global__ __launch_bounds__(256) void fc_reformat(const unsigned short* __restrict__ xb5,
                                                   float* __restrict__ h5T) {
  const int j = blockIdx.x * 256 + threadIdx.x;   // 225792 exact
  const int b = j & 31;
  const int pos = (j >> 5) % 441;
  const int oc = j / (441 * 32);
  h5T[j] = bf2f(xb5[((size_t)pos * 32 + b) * 16 + oc]);
}

// ---------------- fc1: reg-tiled GEMM (unchanged)
__global__ __launch_bounds__(256) void fc1_v2(const float* __restrict__ xt,
                                              const float* __restrict__ w,
                                              const float* __restrict__ bias,
                                              float* __restrict__ out) {
  const int lane = threadIdx.x & 63;
  const int b0 = (threadIdx.x >> 6) * 8;
  const int n0 = blockIdx.x * 8;
  float acc[8][8] = {};
  for (int it = 0; it < 28; ++it) {
    const int kb = it * 256 + lane * 4;
    float4 wf[8], xa[4], xb[4];
    if (kb < 7056) {
      #pragma unroll
      for (int n = 0; n < 8; ++n)
        wf[n] = *(const float4*)&w[(size_t)(n0 + n) * 7056 + kb];
      #pragma unroll
      for (int j = 0; j < 4; ++j) {
        xa[j] = *(const float4*)&xt[(size_t)(kb + j) * 32 + b0];
        xb[j] = *(const float4*)&xt[(size_t)(kb + j) * 32 + b0 + 4];
      }
    } else {
      #pragma unroll
      for (int n = 0; n < 8; ++n) wf[n] = make_float4(0.f, 0.f, 0.f, 0.f);
      #pragma unroll
      for (int j = 0; j < 4; ++j) {
        xa[j] = make_float4(0.f, 0.f, 0.f, 0.f);
        xb[j] = make_float4(0.f, 0.f, 0.f, 0.f);
      }
    }
    #pragma unroll
    for (int n = 0; n < 8; ++n) {
      const float wk[4] = {wf[n].x, wf[n].y, wf[n].z, wf[n].w};
      #pragma unroll
      for (int j = 0; j < 4; ++j) {
        acc[n][0] += wk[j] * xa[j].x;
        acc[n][1] += wk[j] * xa[j].y;
        acc[n][2] += wk[j] * xa[j].z;
        acc[n][3] += wk[j] * xa[j].w;
        acc[n][4] += wk[j] * xb[j].x;
        acc[n][5] += wk[j] * xb[j].y;
        acc[n][6] += wk[j] * xb[j].z;
        acc[n][7] += wk[j] * xb[j].w;
      }
    }
  }
  #pragma unroll
  for (int n = 0; n < 8; ++n)
    #pragma unroll
    for (int c = 0; c < 8; ++c)
      #pragma unroll
      for (int m = 1; m < 64; m <<= 1)
        acc[n][c] += __shfl_xor(acc[n][c], m, 64);
  float val = 0.f;
  #pragma unroll
  for (int n = 0; n < 8; ++n)
    #pragma unroll
    for (int c = 0; c < 8; ++c)
      if (lane == n * 8 + c) val = acc[n][c];
  const int n_l = lane >> 3, b_l = lane & 7;
  out[(size_t)(b0 + b_l) * 4096 + n0 + n_l] = val + bias[n0 + n_l];
}

extern "C" void kernel_launch(void* const* d_in, const int* in_sizes, int n_in,
                              void* d_out, int out_size, void* d_ws, size_t ws_size,
                              hipStream_t stream) {
  const float* x       = (const float*)d_in[0];
  const float* conv1_w = (const float*)d_in[1];
  const float* conv1_b = (const float*)d_in[2];
  const float* conv2_w = (const float*)d_in[3];
  const float* conv2_b = (const float*)d_in[4];
  const float* lc1_w   = (const float*)d_in[5];
  const float* lc1_b   = (const float*)d_in[6];
  const float* lc2_w   = (const float*)d_in[7];
  const float* lc2_b   = (const float*)d_in[8];
  const float* lc3_w   = (const float*)d_in[9];
  const float* lc3_b   = (const float*)d_in[10];
  const float* fc1_w   = (const float*)d_in[11];
  const float* fc1_b   = (const float*)d_in[12];
  float* out = (float*)d_out;
  char* ws = (char*)d_ws;

  // timeline-aware layout (bytes), peak ~78.5 MB:
  unsigned short* xb1 = (unsigned short*)(ws + 0);         //  6,225,920 (dead after conv1)
  unsigned short* wb1 = (unsigned short*)(ws + 6291456);   //     34,816
  unsigned short* c1T = (unsigned short*)(ws + 8388608);   // 41,295,872 (dead after pool_t)
  unsigned short* xb2 = (unsigned short*)(ws + 50331648);  // 10,323,968 (dead after conv2)
  unsigned short* wb2 = (unsigned short*)(ws + 62914560);  //     82,944 (dead after conv2)
  unsigned short* h2b = (unsigned short*)(ws + 67108864);  //  4,064,256 (dead after lc1)
  unsigned short* xb3 = (unsigned short*)(ws + 71303168);  //  3,097,600 (dead after lc2)
  unsigned short* xb4 = (unsigned short*)(ws + 75497472);  //    640,000 (dead after lc3)
  unsigned short* xb5 = (unsigned short*)(ws + 76546048);  //    451,584
  float* h5T          = (float*)(ws + 77594624);           //    903,168

  prep_xb1<<<3040, 256, 0, stream>>>(x, xb1);
  prep_wb1<<<68, 256, 0, stream>>>(conv1_w, wb1);
  conv1_mfma<<<5041, 256, 0, stream>>>(xb1, wb1, conv1_b, c1T);
  pool_t<<<dim3(71, 9), 256, 0, stream>>>(c1T, xb2);
  prep_wb2<<<162, 256, 0, stream>>>(conv2_w, wb2);
  conv2_mfma<<<993, 256, 0, stream>>>(xb2, wb2, conv2_b, h2b);

  lc_mfma2<9, 1, 63, 55><<<757, 256, 0, stream>>>(h2b, lc1_w, lc1_b, xb3);
  lc_mfma2<7, 2, 55, 25><<<157, 256, 0, stream>>>(xb3, lc2_w, lc2_b, xb4);
  lc_mfma2<5, 1, 25, 21><<<111, 256, 0, stream>>>(xb4, lc3_w, lc3_b, xb5);

  fc_reformat<<<882, 256, 0, stream>>>(xb5, h5T);
  fc1_v2<<<512, 256, 0, stream>>>(h5T, fc1_w, fc1_b, out);
}

// Round 16
// 512.157 us; speedup vs baseline: 1.4176x; 1.4176x over previous
//
#include <hip/hip_runtime.h>
#include <cstddef>

typedef __attribute__((ext_vector_type(8))) short bf16x8;
typedef __attribute__((ext_vector_type(8), aligned(8))) short bf16x8a;
typedef __attribute__((ext_vector_type(4))) float f32x4;
typedef __attribute__((ext_vector_type(4))) unsigned short u16x4;

__device__ inline unsigned short f2bf(float f) {
  unsigned int u = __float_as_uint(f);
  unsigned int r = (u + 0x7FFFu + ((u >> 16) & 1u)) >> 16;
  return (unsigned short)r;
}
__device__ inline float bf2f(unsigned short u) {
  return __uint_as_float((unsigned int)u << 16);
}

// ---------------- prep: x (32,3,152,152) f32 -> xb1 bf16 [ih152][iw160][b32][ic4]
// iw >= 152 and ic slot 3 are zero. (b-interleaved so conv1 B-loads coalesce)
__global__ __launch_bounds__(256) void prep_xb1(const float* __restrict__ x,
                                                unsigned short* __restrict__ xb) {
  const int j = blockIdx.x * 256 + threadIdx.x;   // 32*152*160 = 778240 exact
  const int iw = j % 160;
  const int ih = (j / 160) % 152;
  const int b = j / (160 * 152);
  unsigned short v[4] = {0, 0, 0, 0};
  if (iw < 152) {
    #pragma unroll
    for (int ic = 0; ic < 3; ++ic)
      v[ic] = f2bf(x[(size_t)(b * 3 + ic) * 23104 + ih * 152 + iw]);
  }
  *(unsigned long long*)(xb + ((((size_t)ih * 160 + iw) * 32) + b) * 4) =
      *(unsigned long long*)v;
}

// ---------------- prep: conv1 w (32,3,11,11) -> A-table wb1 [step17][kc4][s32][8]
__global__ __launch_bounds__(256) void prep_wb1(const float* __restrict__ w,
                                                unsigned short* __restrict__ wb) {
  const int j = blockIdx.x * 256 + threadIdx.x;   // 17408 exact
  const int e = j & 7;
  const int s = (j >> 3) & 31;
  const int kcj = j >> 8;
  const int kc = kcj & 3, step = kcj >> 2;
  const int t = step * 8 + kc * 2 + (e >> 2);
  const int ics = e & 3;
  const int kh = t / 12, kwp = t - kh * 12;
  float val = 0.f;
  if (t < 132 && kwp < 11 && ics < 3)
    val = w[((s * 3 + ics) * 11 + kh) * 11 + kwp];
  wb[j] = f2bf(val);
}

// ---------------- conv1 via MFMA: writes c1T bf16 [oc32][pos20164][b32].
// B-fragment = two 8-B loads; per instruction 16 b-lanes form 128-B runs.
__global__ __launch_bounds__(256, 4) void conv1_mfma(const unsigned short* __restrict__ xb,
                                                     const unsigned short* __restrict__ wb,
                                                     const float* __restrict__ bias,
                                                     unsigned short* __restrict__ outT) {
  const int lane = threadIdx.x & 63;
  const int wvi = threadIdx.x >> 6;
  const int pos = blockIdx.x * 4 + wvi;           // 5041*4 = 20164 exact
  const int oh = pos / 142, ow = pos % 142;
  const int row = lane & 15;                      // A row (oc) / B col (b)
  const int kc = lane >> 4;                       // k-chunk 0..3
  f32x4 a00 = {0.f, 0.f, 0.f, 0.f}, a01 = a00, a10 = a00, a11 = a00;

  #pragma unroll 2
  for (int j = 0; j < 17; ++j) {
    const int t0 = j * 8 + 2 * kc;                // even tap; pair never crosses kh
    int kh = t0 / 12;
    int kwp = t0 - kh * 12;
    if (t0 >= 132) { kh = 0; kwp = 0; }           // A rows are zero there
    const bf16x8 wa0 = *(const bf16x8*)(wb + (((j * 4 + kc) * 32) + row) * 8);
    const bf16x8 wa1 = *(const bf16x8*)(wb + (((j * 4 + kc) * 32) + 16 + row) * 8);
    const size_t base = (((size_t)(oh + kh) * 160) + (ow + kwp)) * 128;  // elems
    const unsigned short* xp0 = xb + base + row * 4;
    bf16x8 xv0, xv1;
    ((unsigned long long*)&xv0)[0] = *(const unsigned long long*)(xp0);
    ((unsigned long long*)&xv0)[1] = *(const unsigned long long*)(xp0 + 128);
    ((unsigned long long*)&xv1)[0] = *(const unsigned long long*)(xp0 + 64);
    ((unsigned long long*)&xv1)[1] = *(const unsigned long long*)(xp0 + 192);
    a00 = __builtin_amdgcn_mfma_f32_16x16x32_bf16(wa0, xv0, a00, 0, 0, 0);
    a01 = __builtin_amdgcn_mfma_f32_16x16x32_bf16(wa0, xv1, a01, 0, 0, 0);
    a10 = __builtin_amdgcn_mfma_f32_16x16x32_bf16(wa1, xv0, a10, 0, 0, 0);
    a11 = __builtin_amdgcn_mfma_f32_16x16x32_bf16(wa1, xv1, a11, 0, 0, 0);
  }

  #pragma unroll
  for (int r = 0; r < 4; ++r) {
    const int ocl = kc * 4 + r;
    const float bv0 = bias[ocl];
    const float bv1 = bias[16 + ocl];
    outT[((size_t)ocl * 20164 + pos) * 32 + row] = f2bf(fmaxf(a00[r] + bv0, 0.f));
    outT[((size_t)ocl * 20164 + pos) * 32 + 16 + row] = f2bf(fmaxf(a01[r] + bv0, 0.f));
    outT[((size_t)(16 + ocl) * 20164 + pos) * 32 + row] = f2bf(fmaxf(a10[r] + bv1, 0.f));
    outT[((size_t)(16 + ocl) * 20164 + pos) * 32 + 16 + row] = f2bf(fmaxf(a11[r] + bv1, 0.f));
  }
}

// ---------------- fused maxpool(3,2,1) + transpose -> xb2 [pos'5041][b32][c32] bf16
__global__ __launch_bounds__(256) void pool_t(const unsigned short* __restrict__ in,
                                              unsigned short* __restrict__ xb) {
  __shared__ float tile[8][32][33];
  const int ohp = blockIdx.x;
  const int t8 = blockIdx.y;
  const int tid = threadIdx.x;
  const int b = tid & 31, pg = tid >> 5;
  const int owp = min(t8 * 8 + pg, 70);

  for (int c = 0; c < 32; ++c) {
    float m = 0.f;
    #pragma unroll
    for (int kh = 0; kh < 3; ++kh) {
      const int ih = ohp * 2 - 1 + kh;
      if (ih < 0 || ih >= 142) continue;
      #pragma unroll
      for (int kw = 0; kw < 3; ++kw) {
        const int iw = owp * 2 - 1 + kw;
        if (iw < 0 || iw >= 142) continue;
        m = fmaxf(m, bf2f(in[((size_t)c * 20164 + ih * 142 + iw) * 32 + b]));
      }
    }
    tile[pg][b][c] = m;
  }
  __syncthreads();

  if (t8 * 8 + pg < 71) {
    const int posp = ohp * 71 + t8 * 8 + pg;
    #pragma unroll
    for (int cc = 0; cc < 32; cc += 8) {
      bf16x8 pack;
      #pragma unroll
      for (int e = 0; e < 8; ++e) pack[e] = (short)f2bf(tile[pg][b][cc + e]);
      *(bf16x8*)(xb + ((size_t)posp * 32 + b) * 32 + cc) = pack;
    }
  }
}

// ---------------- wb2: conv2 w (16,32,9,9) -> [sp81][oc16][ic32] bf16
__global__ __launch_bounds__(256) void prep_wb2(const float* __restrict__ w,
                                                unsigned short* __restrict__ wb) {
  const int j = blockIdx.x * 256 + threadIdx.x;
  if (j >= 81 * 16 * 32) return;
  const int ic = j & 31, oc = (j >> 5) & 15, sp = j >> 9;
  wb[j] = f2bf(w[(size_t)oc * 2592 + ic * 81 + sp]);
}

// ---------------- conv2 via MFMA; writes h2b bf16 [pos][b32][oc16]
__global__ __launch_bounds__(256) void conv2_mfma(const unsigned short* __restrict__ xb,
                                                  const unsigned short* __restrict__ wb,
                                                  const float* __restrict__ bias,
                                                  unsigned short* __restrict__ outB) {
  const int lane = threadIdx.x & 63;
  const int wvi = threadIdx.x >> 6;
  int pos = blockIdx.x * 4 + wvi;
  if (pos > 3968) pos = 3968;
  const int oh = pos / 63, ow = pos % 63;
  const int row = lane & 15;                      // b column
  const int kc = lane >> 4;
  f32x4 acc0 = {0.f, 0.f, 0.f, 0.f}, acc1 = {0.f, 0.f, 0.f, 0.f};
  const unsigned short* xbase = xb + (size_t)(oh * 71 + ow) * 1024;
  const int aoff = row * 32 + kc * 8;
  const int boff0 = aoff;
  const int boff1 = (row + 16) * 32 + kc * 8;

  #pragma unroll
  for (int kh = 0; kh < 9; ++kh) {
    #pragma unroll
    for (int kw = 0; kw < 9; ++kw) {
      const int sp = kh * 9 + kw;
      const bf16x8 a = *(const bf16x8*)(wb + sp * 512 + aoff);
      const unsigned short* xp = xbase + (kh * 71 + kw) * 1024;
      const bf16x8 b0 = *(const bf16x8*)(xp + boff0);
      const bf16x8 b1 = *(const bf16x8*)(xp + boff1);
      acc0 = __builtin_amdgcn_mfma_f32_16x16x32_bf16(a, b0, acc0, 0, 0, 0);
      acc1 = __builtin_amdgcn_mfma_f32_16x16x32_bf16(a, b1, acc1, 0, 0, 0);
    }
  }

  u16x4 pk0, pk1;
  #pragma unroll
  for (int r = 0; r < 4; ++r) {
    const float bv = bias[kc * 4 + r];
    pk0[r] = f2bf(fmaxf(acc0[r] + bv, 0.f));
    pk1[r] = f2bf(fmaxf(acc1[r] + bv, 0.f));
  }
  *(u16x4*)(outB + (size_t)pos * 512 + row * 16 + kc * 4) = pk0;
  *(u16x4*)(outB + (size_t)pos * 512 + (row + 16) * 16 + kc * 4) = pk1;
}

// ---------------- lc weight prep: w [pos][oc16][ic16][KHW] f32 ->
// wbT bf16 [lpos][pair][oc16][tl2*ic16]; LDS-staged, coalesced read+write.
template <int KH>
__global__ __launch_bounds__(256) void prep_lcw(const float* __restrict__ w,
                                                unsigned short* __restrict__ wbT,
                                                int pos_base) {
  constexpr int KHW = KH * KH;
  constexpr int P = (KHW + 1) / 2;
  __shared__ float ls[8 * 16 * KHW];
  const int tid = threadIdx.x;
  const float* wp = w + (size_t)(pos_base + blockIdx.x) * (256 * KHW);
  unsigned short* ob = wbT + (size_t)blockIdx.x * (P * 512);

  for (int half = 0; half < 2; ++half) {
    __syncthreads();
    for (int j = tid; j < 8 * 16 * KHW; j += 256)
      ls[j] = wp[half * (8 * 16 * KHW) + j];
    __syncthreads();
    for (int j = tid; j < P * 256; j += 256) {
      const int ic = j & 15, tl = (j >> 4) & 1, oc8 = (j >> 5) & 7, pair = j >> 8;
      const int tap = pair * 2 + tl;
      const float v = (tap < KHW) ? ls[(oc8 * 16 + ic) * KHW + tap] : 0.f;
      ob[(size_t)pair * 512 + (half * 8 + oc8) * 32 + tl * 16 + ic] = f2bf(v);
    }
  }
}

// ---------------- lc via MFMA: wave = 1 pos; K = 2 taps x 16 ic per step.
template <int KH, int S, int IH, int OH>
__global__ __launch_bounds__(256) void lc_mfma(const unsigned short* __restrict__ xb,
                                               const unsigned short* __restrict__ wbT,
                                               const float* __restrict__ bias,
                                               unsigned short* __restrict__ out,
                                               int pos_base, int pos_count) {
  constexpr int KHW = KH * KH;
  constexpr int P = (KHW + 1) / 2;
  constexpr int NPOS = OH * OH;
  const int lane = threadIdx.x & 63;
  const int wvi = threadIdx.x >> 6;
  int lpos = blockIdx.x * 4 + wvi;
  if (lpos >= pos_count) lpos = pos_count - 1;
  const int pos = pos_base + lpos;
  const int oh = pos / OH, ow = pos % OH;
  const int bcol = lane & 15;
  const int kc = lane >> 4;
  const int tsel = kc >> 1;
  const int icoff = (kc & 1) * 8;
  f32x4 acc0 = {0.f, 0.f, 0.f, 0.f}, acc1 = {0.f, 0.f, 0.f, 0.f};
  const unsigned short* wp = wbT + (size_t)lpos * (P * 512) + bcol * 32 + kc * 8;
  const int xorg = (oh * S) * IH + ow * S;

  #pragma unroll
  for (int p = 0; p < P; ++p) {
    const int t0 = 2 * p;
    const int t1 = (2 * p + 1 < KHW) ? 2 * p + 1 : 2 * p;
    const int o0 = (t0 / KH) * IH + (t0 % KH);
    const int o1 = (t1 / KH) * IH + (t1 % KH);
    const int osel = tsel ? o1 : o0;
    const bf16x8 a = *(const bf16x8*)(wp + p * 512);
    const unsigned short* xp = xb + (size_t)(xorg + osel) * 512 + icoff;
    const bf16x8 b0 = *(const bf16x8*)(xp + bcol * 16);
    const bf16x8 b1 = *(const bf16x8*)(xp + (bcol + 16) * 16);
    acc0 = __builtin_amdgcn_mfma_f32_16x16x32_bf16(a, b0, acc0, 0, 0, 0);
    acc1 = __builtin_amdgcn_mfma_f32_16x16x32_bf16(a, b1, acc1, 0, 0, 0);
  }

  u16x4 pk0, pk1;
  #pragma unroll
  for (int r = 0; r < 4; ++r) {
    const float bv = bias[(kc * 4 + r) * NPOS + pos];
    pk0[r] = f2bf(fmaxf(acc0[r] + bv, 0.f));
    pk1[r] = f2bf(fmaxf(acc1[r] + bv, 0.f));
  }
  *(u16x4*)(out + (size_t)pos * 512 + bcol * 16 + kc * 4) = pk0;
  *(u16x4*)(out + (size_t)pos * 512 + (bcol + 16) * 16 + kc * 4) = pk1;
}

// ---------------- reformat lc3 out [pos441][b32][oc16] bf16 -> h5T f32 [oc*441+pos][b32]
__global__ __launch_bounds__(256) void fc_reformat(const unsigned short* __restrict__ xb5,
                                                   float* __restrict__ h5T) {
  const int j = blockIdx.x * 256 + threadIdx.x;   // 225792 exact
  const int b = j & 31;
  const int pos = (j >> 5) % 441;
  const int oc = j / (441 * 32);
  h5T[j] = bf2f(xb5[((size_t)pos * 32 + b) * 16 + oc]);
}

// ---------------- fc1: reg-tiled GEMM
__global__ __launch_bounds__(256) void fc1_v2(const float* __restrict__ xt,
                                              const float* __restrict__ w,
                                              const float* __restrict__ bias,
                                              float* __restrict__ out) {
  const int lane = threadIdx.x & 63;
  const int b0 = (threadIdx.x >> 6) * 8;
  const int n0 = blockIdx.x * 8;
  float acc[8][8] = {};
  for (int it = 0; it < 28; ++it) {
    const int kb = it * 256 + lane * 4;
    float4 wf[8], xa[4], xb[4];
    if (kb < 7056) {
      #pragma unroll
      for (int n = 0; n < 8; ++n)
        wf[n] = *(const float4*)&w[(size_t)(n0 + n) * 7056 + kb];
      #pragma unroll
      for (int j = 0; j < 4; ++j) {
        xa[j] = *(const float4*)&xt[(size_t)(kb + j) * 32 + b0];
        xb[j] = *(const float4*)&xt[(size_t)(kb + j) * 32 + b0 + 4];
      }
    } else {
      #pragma unroll
      for (int n = 0; n < 8; ++n) wf[n] = make_float4(0.f, 0.f, 0.f, 0.f);
      #pragma unroll
      for (int j = 0; j < 4; ++j) {
        xa[j] = make_float4(0.f, 0.f, 0.f, 0.f);
        xb[j] = make_float4(0.f, 0.f, 0.f, 0.f);
      }
    }
    #pragma unroll
    for (int n = 0; n < 8; ++n) {
      const float wk[4] = {wf[n].x, wf[n].y, wf[n].z, wf[n].w};
      #pragma unroll
      for (int j = 0; j < 4; ++j) {
        acc[n][0] += wk[j] * xa[j].x;
        acc[n][1] += wk[j] * xa[j].y;
        acc[n][2] += wk[j] * xa[j].z;
        acc[n][3] += wk[j] * xa[j].w;
        acc[n][4] += wk[j] * xb[j].x;
        acc[n][5] += wk[j] * xb[j].y;
        acc[n][6] += wk[j] * xb[j].z;
        acc[n][7] += wk[j] * xb[j].w;
      }
    }
  }
  #pragma unroll
  for (int n = 0; n < 8; ++n)
    #pragma unroll
    for (int c = 0; c < 8; ++c)
      #pragma unroll
      for (int m = 1; m < 64; m <<= 1)
        acc[n][c] += __shfl_xor(acc[n][c], m, 64);
  float val = 0.f;
  #pragma unroll
  for (int n = 0; n < 8; ++n)
    #pragma unroll
    for (int c = 0; c < 8; ++c)
      if (lane == n * 8 + c) val = acc[n][c];
  const int n_l = lane >> 3, b_l = lane & 7;
  out[(size_t)(b0 + b_l) * 4096 + n0 + n_l] = val + bias[n0 + n_l];
}

extern "C" void kernel_launch(void* const* d_in, const int* in_sizes, int n_in,
                              void* d_out, int out_size, void* d_ws, size_t ws_size,
                              hipStream_t stream) {
  const float* x       = (const float*)d_in[0];
  const float* conv1_w = (const float*)d_in[1];
  const float* conv1_b = (const float*)d_in[2];
  const float* conv2_w = (const float*)d_in[3];
  const float* conv2_b = (const float*)d_in[4];
  const float* lc1_w   = (const float*)d_in[5];
  const float* lc1_b   = (const float*)d_in[6];
  const float* lc2_w   = (const float*)d_in[7];
  const float* lc2_b   = (const float*)d_in[8];
  const float* lc3_w   = (const float*)d_in[9];
  const float* lc3_b   = (const float*)d_in[10];
  const float* fc1_w   = (const float*)d_in[11];
  const float* fc1_b   = (const float*)d_in[12];
  float* out = (float*)d_out;
  char* ws = (char*)d_ws;

  // timeline-aware layout (bytes), peak ~78.5 MB:
  unsigned short* xb1 = (unsigned short*)(ws + 0);         //  6,225,920 (dead after conv1)
  unsigned short* wb1 = (unsigned short*)(ws + 6291456);   //     34,816
  unsigned short* c1T = (unsigned short*)(ws + 8388608);   // 41,295,872 (dead after pool_t)
  unsigned short* xb2 = (unsigned short*)(ws + 50331648);  // 10,323,968 (dead after conv2)
  unsigned short* wb2 = (unsigned short*)(ws + 62914560);  //     82,944 (dead after conv2)
  unsigned short* h2b = (unsigned short*)(ws + 67108864);  //  4,064,256 (dead after lc1)
  unsigned short* xb3 = (unsigned short*)(ws + 71303168);  //  3,097,600 (dead after lc2)
  unsigned short* xb4 = (unsigned short*)(ws + 75497472);  //    640,000 (dead after lc3)
  unsigned short* xb5 = (unsigned short*)(ws + 76546048);  //    451,584
  float* h5T          = (float*)(ws + 77594624);           //    903,168
  unsigned short* wbT = (unsigned short*)(ws + 0);         // <= 63,521,792 (lc weight chunks; earlier buffers dead)

  prep_xb1<<<3040, 256, 0, stream>>>(x, xb1);
  prep_wb1<<<68, 256, 0, stream>>>(conv1_w, wb1);
  conv1_mfma<<<5041, 256, 0, stream>>>(xb1, wb1, conv1_b, c1T);
  pool_t<<<dim3(71, 9), 256, 0, stream>>>(c1T, xb2);
  prep_wb2<<<162, 256, 0, stream>>>(conv2_w, wb2);
  conv2_mfma<<<993, 256, 0, stream>>>(xb2, wb2, conv2_b, h2b);

  // lc1 in two weight chunks (63.5 MB each)
  prep_lcw<9><<<1513, 256, 0, stream>>>(lc1_w, wbT, 0);
  lc_mfma<9, 1, 63, 55><<<379, 256, 0, stream>>>(h2b, wbT, lc1_b, xb3, 0, 1513);
  prep_lcw<9><<<1512, 256, 0, stream>>>(lc1_w, wbT, 1513);
  lc_mfma<9, 1, 63, 55><<<378, 256, 0, stream>>>(h2b, wbT, lc1_b, xb3, 1513, 1512);

  prep_lcw<7><<<625, 256, 0, stream>>>(lc2_w, wbT, 0);
  lc_mfma<7, 2, 55, 25><<<157, 256, 0, stream>>>(xb3, wbT, lc2_b, xb4, 0, 625);

  prep_lcw<5><<<441, 256, 0, stream>>>(lc3_w, wbT, 0);
  lc_mfma<5, 1, 25, 21><<<111, 256, 0, stream>>>(xb4, wbT, lc3_b, xb5, 0, 441);

  fc_reformat<<<882, 256, 0, stream>>>(xb5, h5T);
  fc1_v2<<<512, 256, 0, stream>>>(h5T, fc1_w, fc1_b, out);
}

// Round 17
// 440.112 us; speedup vs baseline: 1.6496x; 1.1637x over previous
//
#include <hip/hip_runtime.h>
#include <cstddef>

typedef __attribute__((ext_vector_type(8))) short bf16x8;
typedef __attribute__((ext_vector_type(8), aligned(8))) short bf16x8a;
typedef __attribute__((ext_vector_type(4))) float f32x4;
typedef __attribute__((ext_vector_type(4))) unsigned short u16x4;
typedef __attribute__((ext_vector_type(8))) unsigned short u16x8;

__device__ inline unsigned short f2bf(float f) {
  unsigned int u = __float_as_uint(f);
  unsigned int r = (u + 0x7FFFu + ((u >> 16) & 1u)) >> 16;
  return (unsigned short)r;
}
__device__ inline float bf2f(unsigned short u) {
  return __uint_as_float((unsigned int)u << 16);
}

// ---------------- prep: x (32,3,152,152) f32 -> xb1 bf16 [ih152][iw160][b32][ic4]
__global__ __launch_bounds__(256) void prep_xb1(const float* __restrict__ x,
                                                unsigned short* __restrict__ xb) {
  const int j = blockIdx.x * 256 + threadIdx.x;   // 32*152*160 = 778240 exact
  const int iw = j % 160;
  const int ih = (j / 160) % 152;
  const int b = j / (160 * 152);
  unsigned short v[4] = {0, 0, 0, 0};
  if (iw < 152) {
    #pragma unroll
    for (int ic = 0; ic < 3; ++ic)
      v[ic] = f2bf(x[(size_t)(b * 3 + ic) * 23104 + ih * 152 + iw]);
  }
  *(unsigned long long*)(xb + ((((size_t)ih * 160 + iw) * 32) + b) * 4) =
      *(unsigned long long*)v;
}

// ---------------- prep: conv1 w (32,3,11,11) -> A-table wb1 [step17][kc4][s32][8]
__global__ __launch_bounds__(256) void prep_wb1(const float* __restrict__ w,
                                                unsigned short* __restrict__ wb) {
  const int j = blockIdx.x * 256 + threadIdx.x;   // 17408 exact
  const int e = j & 7;
  const int s = (j >> 3) & 31;
  const int kcj = j >> 8;
  const int kc = kcj & 3, step = kcj >> 2;
  const int t = step * 8 + kc * 2 + (e >> 2);
  const int ics = e & 3;
  const int kh = t / 12, kwp = t - kh * 12;
  float val = 0.f;
  if (t < 132 && kwp < 11 && ics < 3)
    val = w[((s * 3 + ics) * 11 + kh) * 11 + kwp];
  wb[j] = f2bf(val);
}

// ---------------- conv1 via MFMA: writes c1B bf16 [pos20164][b32][oc32].
// B-fragment = two 8-B loads (coalesced 128-B runs); epilogue = 4 x u16x4 stores
// (wave covers contiguous 2 KB).
__global__ __launch_bounds__(256, 4) void conv1_mfma(const unsigned short* __restrict__ xb,
                                                     const unsigned short* __restrict__ wb,
                                                     const float* __restrict__ bias,
                                                     unsigned short* __restrict__ outB) {
  const int lane = threadIdx.x & 63;
  const int wvi = threadIdx.x >> 6;
  const int pos = blockIdx.x * 4 + wvi;           // 5041*4 = 20164 exact
  const int oh = pos / 142, ow = pos % 142;
  const int row = lane & 15;                      // A row (oc) / B col (b)
  const int kc = lane >> 4;                       // k-chunk 0..3
  f32x4 a00 = {0.f, 0.f, 0.f, 0.f}, a01 = a00, a10 = a00, a11 = a00;

  #pragma unroll 2
  for (int j = 0; j < 17; ++j) {
    const int t0 = j * 8 + 2 * kc;                // even tap; pair never crosses kh
    int kh = t0 / 12;
    int kwp = t0 - kh * 12;
    if (t0 >= 132) { kh = 0; kwp = 0; }           // A rows are zero there
    const bf16x8 wa0 = *(const bf16x8*)(wb + (((j * 4 + kc) * 32) + row) * 8);
    const bf16x8 wa1 = *(const bf16x8*)(wb + (((j * 4 + kc) * 32) + 16 + row) * 8);
    const size_t base = (((size_t)(oh + kh) * 160) + (ow + kwp)) * 128;  // elems
    const unsigned short* xp0 = xb + base + row * 4;
    bf16x8 xv0, xv1;
    ((unsigned long long*)&xv0)[0] = *(const unsigned long long*)(xp0);
    ((unsigned long long*)&xv0)[1] = *(const unsigned long long*)(xp0 + 128);
    ((unsigned long long*)&xv1)[0] = *(const unsigned long long*)(xp0 + 64);
    ((unsigned long long*)&xv1)[1] = *(const unsigned long long*)(xp0 + 192);
    a00 = __builtin_amdgcn_mfma_f32_16x16x32_bf16(wa0, xv0, a00, 0, 0, 0);
    a01 = __builtin_amdgcn_mfma_f32_16x16x32_bf16(wa0, xv1, a01, 0, 0, 0);
    a10 = __builtin_amdgcn_mfma_f32_16x16x32_bf16(wa1, xv0, a10, 0, 0, 0);
    a11 = __builtin_amdgcn_mfma_f32_16x16x32_bf16(wa1, xv1, a11, 0, 0, 0);
  }

  // C/D: col(lane&15)=b, row=oc=kc*4+r (a00/a01: oc 0-15; a10/a11: oc 16-31;
  // a00/a10: b 0-15; a01/a11: b 16-31). Layout [pos][b][oc].
  unsigned short* ob = outB + (size_t)pos * 1024;
  u16x4 p00, p01, p10, p11;
  #pragma unroll
  for (int r = 0; r < 4; ++r) {
    const float bv0 = bias[kc * 4 + r];
    const float bv1 = bias[16 + kc * 4 + r];
    p00[r] = f2bf(fmaxf(a00[r] + bv0, 0.f));
    p01[r] = f2bf(fmaxf(a01[r] + bv0, 0.f));
    p10[r] = f2bf(fmaxf(a10[r] + bv1, 0.f));
    p11[r] = f2bf(fmaxf(a11[r] + bv1, 0.f));
  }
  *(u16x4*)(ob + row * 32 + kc * 4) = p00;
  *(u16x4*)(ob + (row + 16) * 32 + kc * 4) = p01;
  *(u16x4*)(ob + row * 32 + 16 + kc * 4) = p10;
  *(u16x4*)(ob + (row + 16) * 32 + 16 + kc * 4) = p11;
}

// ---------------- pool_t2: maxpool(3,2,1) on c1B [pos][b32][oc32] -> xb2
// [pos'5041][b32][ic32]. Vectorized 64-B loads; integer max valid (relu >= 0).
__global__ __launch_bounds__(256) void pool_t2(const unsigned short* __restrict__ in,
                                               unsigned short* __restrict__ xb) {
  const int tid = threadIdx.x;
  const int b = tid & 31, pg = tid >> 5;
  const int posp = blockIdx.x * 8 + pg;
  if (posp >= 5041) return;
  const int ohp = posp / 71, owp = posp % 71;
  u16x8 m[4];
  #pragma unroll
  for (int q = 0; q < 4; ++q)
    #pragma unroll
    for (int e = 0; e < 8; ++e) m[q][e] = 0;

  #pragma unroll
  for (int kh = 0; kh < 3; ++kh) {
    const int ih = ohp * 2 - 1 + kh;
    if (ih < 0 || ih >= 142) continue;
    #pragma unroll
    for (int kw = 0; kw < 3; ++kw) {
      const int iw = owp * 2 - 1 + kw;
      if (iw < 0 || iw >= 142) continue;
      const u16x8* p =
          (const u16x8*)(in + (((size_t)(ih * 142 + iw)) * 32 + b) * 32);
      #pragma unroll
      for (int q = 0; q < 4; ++q) {
        const u16x8 v = p[q];
        #pragma unroll
        for (int e = 0; e < 8; ++e) m[q][e] = (v[e] > m[q][e]) ? v[e] : m[q][e];
      }
    }
  }
  u16x8* o = (u16x8*)(xb + ((size_t)posp * 32 + b) * 32);
  #pragma unroll
  for (int q = 0; q < 4; ++q) o[q] = m[q];
}

// ---------------- wb2: conv2 w (16,32,9,9) -> [sp81][oc16][ic32] bf16
__global__ __launch_bounds__(256) void prep_wb2(const float* __restrict__ w,
                                                unsigned short* __restrict__ wb) {
  const int j = blockIdx.x * 256 + threadIdx.x;
  if (j >= 81 * 16 * 32) return;
  const int ic = j & 31, oc = (j >> 5) & 15, sp = j >> 9;
  wb[j] = f2bf(w[(size_t)oc * 2592 + ic * 81 + sp]);
}

// ---------------- conv2 via MFMA; writes h2b bf16 [pos][b32][oc16]
__global__ __launch_bounds__(256) void conv2_mfma(const unsigned short* __restrict__ xb,
                                                  const unsigned short* __restrict__ wb,
                                                  const float* __restrict__ bias,
                                                  unsigned short* __restrict__ outB) {
  const int lane = threadIdx.x & 63;
  const int wvi = threadIdx.x >> 6;
  int pos = blockIdx.x * 4 + wvi;
  if (pos > 3968) pos = 3968;
  const int oh = pos / 63, ow = pos % 63;
  const int row = lane & 15;                      // b column
  const int kc = lane >> 4;
  f32x4 acc0 = {0.f, 0.f, 0.f, 0.f}, acc1 = {0.f, 0.f, 0.f, 0.f};
  const unsigned short* xbase = xb + (size_t)(oh * 71 + ow) * 1024;
  const int aoff = row * 32 + kc * 8;
  const int boff0 = aoff;
  const int boff1 = (row + 16) * 32 + kc * 8;

  #pragma unroll
  for (int kh = 0; kh < 9; ++kh) {
    #pragma unroll
    for (int kw = 0; kw < 9; ++kw) {
      const int sp = kh * 9 + kw;
      const bf16x8 a = *(const bf16x8*)(wb + sp * 512 + aoff);
      const unsigned short* xp = xbase + (kh * 71 + kw) * 1024;
      const bf16x8 b0 = *(const bf16x8*)(xp + boff0);
      const bf16x8 b1 = *(const bf16x8*)(xp + boff1);
      acc0 = __builtin_amdgcn_mfma_f32_16x16x32_bf16(a, b0, acc0, 0, 0, 0);
      acc1 = __builtin_amdgcn_mfma_f32_16x16x32_bf16(a, b1, acc1, 0, 0, 0);
    }
  }

  u16x4 pk0, pk1;
  #pragma unroll
  for (int r = 0; r < 4; ++r) {
    const float bv = bias[kc * 4 + r];
    pk0[r] = f2bf(fmaxf(acc0[r] + bv, 0.f));
    pk1[r] = f2bf(fmaxf(acc1[r] + bv, 0.f));
  }
  *(u16x4*)(outB + (size_t)pos * 512 + row * 16 + kc * 4) = pk0;
  *(u16x4*)(outB + (size_t)pos * 512 + (row + 16) * 16 + kc * 4) = pk1;
}

// ---------------- lc weight prep: w [pos][oc16][ic16][KHW] f32 ->
// wbT bf16 [lpos][pair][oc16][tl2*ic16]; LDS-staged, coalesced read+write.
template <int KH>
__global__ __launch_bounds__(256) void prep_lcw(const float* __restrict__ w,
                                                unsigned short* __restrict__ wbT,
                                                int pos_base) {
  constexpr int KHW = KH * KH;
  constexpr int P = (KHW + 1) / 2;
  __shared__ float ls[8 * 16 * KHW];
  const int tid = threadIdx.x;
  const float* wp = w + (size_t)(pos_base + blockIdx.x) * (256 * KHW);
  unsigned short* ob = wbT + (size_t)blockIdx.x * (P * 512);

  for (int half = 0; half < 2; ++half) {
    __syncthreads();
    for (int j = tid; j < 8 * 16 * KHW; j += 256)
      ls[j] = wp[half * (8 * 16 * KHW) + j];
    __syncthreads();
    for (int j = tid; j < P * 256; j += 256) {
      const int ic = j & 15, tl = (j >> 4) & 1, oc8 = (j >> 5) & 7, pair = j >> 8;
      const int tap = pair * 2 + tl;
      const float v = (tap < KHW) ? ls[(oc8 * 16 + ic) * KHW + tap] : 0.f;
      ob[(size_t)pair * 512 + (half * 8 + oc8) * 32 + tl * 16 + ic] = f2bf(v);
    }
  }
}

// ---------------- lc via MFMA: wave = 1 pos; K = 2 taps x 16 ic per step.
template <int KH, int S, int IH, int OH>
__global__ __launch_bounds__(256) void lc_mfma(const unsigned short* __restrict__ xb,
                                               const unsigned short* __restrict__ wbT,
                                               const float* __restrict__ bias,
                                               unsigned short* __restrict__ out,
                                               int pos_base, int pos_count) {
  constexpr int KHW = KH * KH;
  constexpr int P = (KHW + 1) / 2;
  constexpr int NPOS = OH * OH;
  const int lane = threadIdx.x & 63;
  const int wvi = threadIdx.x >> 6;
  int lpos = blockIdx.x * 4 + wvi;
  if (lpos >= pos_count) lpos = pos_count - 1;
  const int pos = pos_base + lpos;
  const int oh = pos / OH, ow = pos % OH;
  const int bcol = lane & 15;
  const int kc = lane >> 4;
  const int tsel = kc >> 1;
  const int icoff = (kc & 1) * 8;
  f32x4 acc0 = {0.f, 0.f, 0.f, 0.f}, acc1 = {0.f, 0.f, 0.f, 0.f};
  const unsigned short* wp = wbT + (size_t)lpos * (P * 512) + bcol * 32 + kc * 8;
  const int xorg = (oh * S) * IH + ow * S;

  #pragma unroll
  for (int p = 0; p < P; ++p) {
    const int t0 = 2 * p;
    const int t1 = (2 * p + 1 < KHW) ? 2 * p + 1 : 2 * p;
    const int o0 = (t0 / KH) * IH + (t0 % KH);
    const int o1 = (t1 / KH) * IH + (t1 % KH);
    const int osel = tsel ? o1 : o0;
    const bf16x8 a = *(const bf16x8*)(wp + p * 512);
    const unsigned short* xp = xb + (size_t)(xorg + osel) * 512 + icoff;
    const bf16x8 b0 = *(const bf16x8*)(xp + bcol * 16);
    const bf16x8 b1 = *(const bf16x8*)(xp + (bcol + 16) * 16);
    acc0 = __builtin_amdgcn_mfma_f32_16x16x32_bf16(a, b0, acc0, 0, 0, 0);
    acc1 = __builtin_amdgcn_mfma_f32_16x16x32_bf16(a, b1, acc1, 0, 0, 0);
  }

  u16x4 pk0, pk1;
  #pragma unroll
  for (int r = 0; r < 4; ++r) {
    const float bv = bias[(kc * 4 + r) * NPOS + pos];
    pk0[r] = f2bf(fmaxf(acc0[r] + bv, 0.f));
    pk1[r] = f2bf(fmaxf(acc1[r] + bv, 0.f));
  }
  *(u16x4*)(out + (size_t)pos * 512 + bcol * 16 + kc * 4) = pk0;
  *(u16x4*)(out + (size_t)pos * 512 + (bcol + 16) * 16 + kc * 4) = pk1;
}

// ---------------- reformat lc3 out [pos441][b32][oc16] bf16 -> h5T f32 [oc*441+pos][b32]
__global__ __launch_bounds__(256) void fc_reformat(const unsigned short* __restrict__ xb5,
                                                   float* __restrict__ h5T) {
  const int j = blockIdx.x * 256 + threadIdx.x;   // 225792 exact
  const int b = j & 31;
  const int pos = (j >> 5) % 441;
  const int oc = j / (441 * 32);
  h5T[j] = bf2f(xb5[((size_t)pos * 32 + b) * 16 + oc]);
}

// ---------------- fc1: reg-tiled GEMM
__global__ __launch_bounds__(256) void fc1_v2(const float* __restrict__ xt,
                                              const float* __restrict__ w,
                                              const float* __restrict__ bias,
                                              float* __restrict__ out) {
  const int lane = threadIdx.x & 63;
  const int b0 = (threadIdx.x >> 6) * 8;
  const int n0 = blockIdx.x * 8;
  float acc[8][8] = {};
  for (int it = 0; it < 28; ++it) {
    const int kb = it * 256 + lane * 4;
    float4 wf[8], xa[4], xb[4];
    if (kb < 7056) {
      #pragma unroll
      for (int n = 0; n < 8; ++n)
        wf[n] = *(const float4*)&w[(size_t)(n0 + n) * 7056 + kb];
      #pragma unroll
      for (int j = 0; j < 4; ++j) {
        xa[j] = *(const float4*)&xt[(size_t)(kb + j) * 32 + b0];
        xb[j] = *(const float4*)&xt[(size_t)(kb + j) * 32 + b0 + 4];
      }
    } else {
      #pragma unroll
      for (int n = 0; n < 8; ++n) wf[n] = make_float4(0.f, 0.f, 0.f, 0.f);
      #pragma unroll
      for (int j = 0; j < 4; ++j) {
        xa[j] = make_float4(0.f, 0.f, 0.f, 0.f);
        xb[j] = make_float4(0.f, 0.f, 0.f, 0.f);
      }
    }
    #pragma unroll
    for (int n = 0; n < 8; ++n) {
      const float wk[4] = {wf[n].x, wf[n].y, wf[n].z, wf[n].w};
      #pragma unroll
      for (int j = 0; j < 4; ++j) {
        acc[n][0] += wk[j] * xa[j].x;
        acc[n][1] += wk[j] * xa[j].y;
        acc[n][2] += wk[j] * xa[j].z;
        acc[n][3] += wk[j] * xa[j].w;
        acc[n][4] += wk[j] * xb[j].x;
        acc[n][5] += wk[j] * xb[j].y;
        acc[n][6] += wk[j] * xb[j].z;
        acc[n][7] += wk[j] * xb[j].w;
      }
    }
  }
  #pragma unroll
  for (int n = 0; n < 8; ++n)
    #pragma unroll
    for (int c = 0; c < 8; ++c)
      #pragma unroll
      for (int m = 1; m < 64; m <<= 1)
        acc[n][c] += __shfl_xor(acc[n][c], m, 64);
  float val = 0.f;
  #pragma unroll
  for (int n = 0; n < 8; ++n)
    #pragma unroll
    for (int c = 0; c < 8; ++c)
      if (lane == n * 8 + c) val = acc[n][c];
  const int n_l = lane >> 3, b_l = lane & 7;
  out[(size_t)(b0 + b_l) * 4096 + n0 + n_l] = val + bias[n0 + n_l];
}

extern "C" void kernel_launch(void* const* d_in, const int* in_sizes, int n_in,
                              void* d_out, int out_size, void* d_ws, size_t ws_size,
                              hipStream_t stream) {
  const float* x       = (const float*)d_in[0];
  const float* conv1_w = (const float*)d_in[1];
  const float* conv1_b = (const float*)d_in[2];
  const float* conv2_w = (const float*)d_in[3];
  const float* conv2_b = (const float*)d_in[4];
  const float* lc1_w   = (const float*)d_in[5];
  const float* lc1_b   = (const float*)d_in[6];
  const float* lc2_w   = (const float*)d_in[7];
  const float* lc2_b   = (const float*)d_in[8];
  const float* lc3_w   = (const float*)d_in[9];
  const float* lc3_b   = (const float*)d_in[10];
  const float* fc1_w   = (const float*)d_in[11];
  const float* fc1_b   = (const float*)d_in[12];
  float* out = (float*)d_out;
  char* ws = (char*)d_ws;

  // timeline-aware layout (bytes), peak ~78.5 MB:
  unsigned short* xb1 = (unsigned short*)(ws + 0);         //  6,225,920 (dead after conv1)
  unsigned short* wb1 = (unsigned short*)(ws + 6291456);   //     34,816
  unsigned short* c1B = (unsigned short*)(ws + 8388608);   // 41,295,872 (dead after pool_t2)
  unsigned short* xb2 = (unsigned short*)(ws + 50331648);  // 10,323,968 (dead after conv2)
  unsigned short* wb2 = (unsigned short*)(ws + 62914560);  //     82,944 (dead after conv2)
  unsigned short* h2b = (unsigned short*)(ws + 67108864);  //  4,064,256 (dead after lc1)
  unsigned short* xb3 = (unsigned short*)(ws + 71303168);  //  3,097,600 (dead after lc2)
  unsigned short* xb4 = (unsigned short*)(ws + 75497472);  //    640,000 (dead after lc3)
  unsigned short* xb5 = (unsigned short*)(ws + 76546048);  //    451,584
  float* h5T          = (float*)(ws + 77594624);           //    903,168
  unsigned short* wbT = (unsigned short*)(ws + 0);         // <= 63,521,792 (lc weight chunks; earlier buffers dead)

  prep_xb1<<<3040, 256, 0, stream>>>(x, xb1);
  prep_wb1<<<68, 256, 0, stream>>>(conv1_w, wb1);
  conv1_mfma<<<5041, 256, 0, stream>>>(xb1, wb1, conv1_b, c1B);
  pool_t2<<<631, 256, 0, stream>>>(c1B, xb2);
  prep_wb2<<<162, 256, 0, stream>>>(conv2_w, wb2);
  conv2_mfma<<<993, 256, 0, stream>>>(xb2, wb2, conv2_b, h2b);

  // lc1 in two weight chunks (63.5 MB each)
  prep_lcw<9><<<1513, 256, 0, stream>>>(lc1_w, wbT, 0);
  lc_mfma<9, 1, 63, 55><<<379, 256, 0, stream>>>(h2b, wbT, lc1_b, xb3, 0, 1513);
  prep_lcw<9><<<1512, 256, 0, stream>>>(lc1_w, wbT, 1513);
  lc_mfma<9, 1, 63, 55><<<378, 256, 0, stream>>>(h2b, wbT, lc1_b, xb3, 1513, 1512);

  prep_lcw<7><<<625, 256, 0, stream>>>(lc2_w, wbT, 0);
  lc_mfma<7, 2, 55, 25><<<157, 256, 0, stream>>>(xb3, wbT, lc2_b, xb4, 0, 625);

  prep_lcw<5><<<441, 256, 0, stream>>>(lc3_w, wbT, 0);
  lc_mfma<5, 1, 25, 21><<<111, 256, 0, stream>>>(xb4, wbT, lc3_b, xb5, 0, 441);

  fc_reformat<<<882, 256, 0, stream>>>(xb5, h5T);
  fc1_v2<<<512, 256, 0, stream>>>(h5T, fc1_w, fc1_b, out);
}